// Round 1
// baseline (2357.115 us; speedup 1.0000x reference)
//
#include <hip/hip_runtime.h>

#define NN 100000
#define EE 1600000
#define C 256
#define OUTC 10
#define NG 64
#define NODES_PER_BLOCK 8

// ---------------- degree histogram (in-degree, real edges only) ----------------
__global__ void degree_kernel(const int* __restrict__ ei, int* __restrict__ indeg) {
    int e = blockIdx.x * blockDim.x + threadIdx.x;
    if (e < EE) {
        int d = ei[EE + e];   // dst row of edge_index [2,E]
        atomicAdd(&indeg[d], 1);
    }
}

// ---------------- per-graph node counts (batch is int) ----------------
__global__ void count_kernel(const int* __restrict__ batch, float* __restrict__ cnt) {
    int i = blockIdx.x * blockDim.x + threadIdx.x;
    if (i < NN) atomicAdd(&cnt[batch[i]], 1.0f);
}

// ---------------- single-block exclusive scan: rowstart[0..NN] ----------------
__global__ void scan_kernel(const int* __restrict__ indeg, int* __restrict__ rowstart) {
    __shared__ int lds[1024];
    __shared__ int s_carry;
    if (threadIdx.x == 0) s_carry = 0;
    __syncthreads();
    const int nchunks = (NN + 1023) / 1024;
    for (int ch = 0; ch < nchunks; ch++) {
        int i = ch * 1024 + threadIdx.x;
        int v = (i < NN) ? indeg[i] : 0;
        lds[threadIdx.x] = v;
        __syncthreads();
        for (int off = 1; off < 1024; off <<= 1) {
            int t = (threadIdx.x >= off) ? lds[threadIdx.x - off] : 0;
            __syncthreads();
            lds[threadIdx.x] += t;
            __syncthreads();
        }
        int incl = lds[threadIdx.x];
        int carry = s_carry;
        if (i < NN) rowstart[i] = carry + incl - v;   // exclusive
        __syncthreads();
        if (threadIdx.x == 1023) s_carry = carry + lds[1023];
        __syncthreads();
    }
    if (threadIdx.x == 0) rowstart[NN] = s_carry;
}

// ---------------- CSR fill: csrcol[rowstart[d] + cursor[d]++] = src ----------------
__global__ void fill_kernel(const int* __restrict__ ei, const int* __restrict__ rowstart,
                            int* __restrict__ cursor, int* __restrict__ csrcol) {
    int e = blockIdx.x * blockDim.x + threadIdx.x;
    if (e < EE) {
        int s = ei[e];
        int d = ei[EE + e];
        int p = atomicAdd(&cursor[d], 1);
        csrcol[rowstart[d] + p] = s;
    }
}

// ---------------- dinv = rsqrt(indeg + 1) (self-loop included) ----------------
__global__ void dinv_kernel(const int* __restrict__ indeg, float* __restrict__ dinv) {
    int i = blockIdx.x * blockDim.x + threadIdx.x;
    if (i < NN) dinv[i] = rsqrtf((float)indeg[i] + 1.0f);
}

// ---------------- g = (x @ W1) * dinv[row]  (fp32, 64 rows/block) ----------------
__global__ __launch_bounds__(256) void gemm_kernel(const float* __restrict__ x,
                                                   const float* __restrict__ W1,
                                                   const float* __restrict__ dinv,
                                                   float* __restrict__ g) {
    __shared__ float xs[64][33];      // 64 rows x 32 k, padded
    __shared__ float wl[32][C];       // 32 k x 256 cols
    const int row0 = blockIdx.x * 64;
    const int c = threadIdx.x;        // this thread's output column
    float acc[64];
    #pragma unroll
    for (int r = 0; r < 64; r++) acc[r] = 0.0f;

    for (int k0 = 0; k0 < C; k0 += 32) {
        for (int i = threadIdx.x; i < 32 * C; i += 256) {
            int kk = i >> 8, cc = i & 255;
            wl[kk][cc] = W1[(k0 + kk) * C + cc];
        }
        for (int i = threadIdx.x; i < 64 * 32; i += 256) {
            int rr = i >> 5, kk = i & 31;
            int row = row0 + rr;
            xs[rr][kk] = (row < NN) ? x[(size_t)row * C + k0 + kk] : 0.0f;
        }
        __syncthreads();
        for (int kk = 0; kk < 32; kk++) {
            float w = wl[kk][c];
            #pragma unroll
            for (int r = 0; r < 64; r++) acc[r] += xs[r][kk] * w;
        }
        __syncthreads();
    }
    #pragma unroll
    for (int r = 0; r < 64; r++) {
        int row = row0 + r;
        if (row < NN) g[(size_t)row * C + c] = acc[r] * dinv[row];
    }
}

// ---------------- aggregate + relu + fused mean-pool partial sums ----------------
__global__ __launch_bounds__(256) void agg_pool_kernel(const float* __restrict__ g,
                                                       const int* __restrict__ rowstart,
                                                       const int* __restrict__ csrcol,
                                                       const float* __restrict__ dinv,
                                                       const float* __restrict__ b1,
                                                       const int* __restrict__ batch,
                                                       float* __restrict__ sums) {
    __shared__ int eld[2048];
    const int c = threadIdx.x;
    const int node0 = blockIdx.x * NODES_PER_BLOCK;
    const int node1 = min(node0 + NODES_PER_BLOCK, NN);
    const int e_begin = rowstart[node0];
    const int e_end = rowstart[node1];
    const int ecount = e_end - e_begin;
    const bool use_lds = (ecount <= 2048);
    if (use_lds) {
        for (int e = threadIdx.x; e < ecount; e += 256) eld[e] = csrcol[e_begin + e];
    }
    __syncthreads();

    const float bc = b1[c];
    float pool = 0.0f;
    int curb = -1;
    for (int i = node0; i < node1; i++) {
        int bi = batch[i];
        if (bi != curb) {
            if (curb >= 0) atomicAdd(&sums[curb * C + c], pool);
            curb = bi;
            pool = 0.0f;
        }
        float s = g[(size_t)i * C + c];     // self-loop term (g = h*dinv)
        int r0 = rowstart[i], r1 = rowstart[i + 1];
        if (use_lds) {
            for (int e = r0 - e_begin; e < r1 - e_begin; e++)
                s += g[(size_t)eld[e] * C + c];
        } else {
            for (int e = r0; e < r1; e++)
                s += g[(size_t)csrcol[e] * C + c];
        }
        float a = dinv[i] * s + bc;
        pool += fmaxf(a, 0.0f);
    }
    if (curb >= 0) atomicAdd(&sums[curb * C + c], pool);
}

// ---------------- pooled = sums/cnt; out = pooled @ W2 + b2 ----------------
__global__ __launch_bounds__(256) void final_kernel(const float* __restrict__ sums,
                                                    const float* __restrict__ cnt,
                                                    const float* __restrict__ W2,
                                                    const float* __restrict__ b2,
                                                    float* __restrict__ out) {
    __shared__ float p[C];
    int gi = blockIdx.x;
    float cdiv = fmaxf(cnt[gi], 1.0f);
    p[threadIdx.x] = sums[gi * C + threadIdx.x] / cdiv;
    __syncthreads();
    if (threadIdx.x < OUTC) {
        float acc = b2[threadIdx.x];
        for (int k = 0; k < C; k++) acc += p[k] * W2[k * OUTC + threadIdx.x];
        out[gi * OUTC + threadIdx.x] = acc;
    }
}

extern "C" void kernel_launch(void* const* d_in, const int* in_sizes, int n_in,
                              void* d_out, int out_size, void* d_ws, size_t ws_size,
                              hipStream_t stream) {
    const float* x     = (const float*)d_in[0];
    const int*   ei    = (const int*)d_in[1];   // [2, E] row-major
    const int*   batch = (const int*)d_in[2];
    const float* W1    = (const float*)d_in[3];
    const float* b1    = (const float*)d_in[4];
    const float* W2    = (const float*)d_in[5];
    const float* b2    = (const float*)d_in[6];
    float* out = (float*)d_out;

    // workspace carve-up (256B aligned)
    char* w = (char*)d_ws;
    size_t off = 0;
    auto carve = [&](size_t bytes) {
        void* p = w + off;
        off = (off + bytes + 255) & ~(size_t)255;
        return p;
    };
    float* g        = (float*)carve((size_t)NN * C * 4);
    int*   indeg    = (int*)  carve((size_t)NN * 4);
    int*   rowstart = (int*)  carve((size_t)(NN + 1) * 4);
    int*   cursor   = (int*)  carve((size_t)NN * 4);
    float* dinv     = (float*)carve((size_t)NN * 4);
    int*   csrcol   = (int*)  carve((size_t)EE * 4);
    float* sums     = (float*)carve((size_t)NG * C * 4);
    float* cnt      = (float*)carve((size_t)NG * 4);

    // zero the accumulator regions (ws is poisoned 0xAA before every launch)
    hipMemsetAsync(indeg, 0, (size_t)NN * 4, stream);
    hipMemsetAsync(cursor, 0, (size_t)NN * 4, stream);
    hipMemsetAsync(sums, 0, (size_t)NG * C * 4, stream);
    hipMemsetAsync(cnt, 0, (size_t)NG * 4, stream);

    degree_kernel<<<(EE + 255) / 256, 256, 0, stream>>>(ei, indeg);
    count_kernel<<<(NN + 255) / 256, 256, 0, stream>>>(batch, cnt);
    scan_kernel<<<1, 1024, 0, stream>>>(indeg, rowstart);
    fill_kernel<<<(EE + 255) / 256, 256, 0, stream>>>(ei, rowstart, cursor, csrcol);
    dinv_kernel<<<(NN + 255) / 256, 256, 0, stream>>>(indeg, dinv);
    gemm_kernel<<<(NN + 63) / 64, 256, 0, stream>>>(x, W1, dinv, g);
    agg_pool_kernel<<<(NN + NODES_PER_BLOCK - 1) / NODES_PER_BLOCK, 256, 0, stream>>>(
        g, rowstart, csrcol, dinv, b1, batch, sums);
    final_kernel<<<NG, 256, 0, stream>>>(sums, cnt, W2, b2, out);
}

// Round 2
// 1455.542 us; speedup vs baseline: 1.6194x; 1.6194x over previous
//
#include <hip/hip_runtime.h>

#define NN 100000
#define EE 1600000
#define C 256
#define OUTC 10
#define NG 64
#define NODES_PER_BLOCK 8

#define BM 64
#define BK 16
#define XPAD 4        // xs row stride 68 floats: keeps float4 alignment, 2-way-max bank aliasing (free)

#define SB 1024
#define NB ((NN + SB - 1) / SB)

// ---------------- degree histogram (in-degree, real edges only) ----------------
__global__ void degree_kernel(const int* __restrict__ ei, int* __restrict__ indeg) {
    int e = blockIdx.x * blockDim.x + threadIdx.x;
    if (e < EE) {
        int d = ei[EE + e];   // dst row of edge_index [2,E]
        atomicAdd(&indeg[d], 1);
    }
}

// ---------------- per-graph node counts ----------------
__global__ void count_kernel(const int* __restrict__ batch, float* __restrict__ cnt) {
    int i = blockIdx.x * blockDim.x + threadIdx.x;
    if (i < NN) atomicAdd(&cnt[batch[i]], 1.0f);
}

// ---------------- hierarchical exclusive scan of indeg -> rowstart ----------------
__global__ __launch_bounds__(256) void partial_sum_kernel(const int* __restrict__ indeg,
                                                          int* __restrict__ bsum) {
    __shared__ int red[256];
    const int b = blockIdx.x;
    const int t = threadIdx.x;
    int base = b * SB + t * 4;
    int s = 0;
    #pragma unroll
    for (int j = 0; j < 4; j++) {
        int i = base + j;
        if (i < NN) s += indeg[i];
    }
    red[t] = s;
    __syncthreads();
    for (int off = 128; off > 0; off >>= 1) {
        if (t < off) red[t] += red[t + off];
        __syncthreads();
    }
    if (t == 0) bsum[b] = red[0];
}

__global__ void scan_partials_kernel(const int* __restrict__ bsum, int* __restrict__ boff) {
    __shared__ int lds[NB];
    int t = threadIdx.x;
    if (t < NB) lds[t] = bsum[t];
    __syncthreads();
    if (t == 0) {
        int acc = 0;
        for (int i = 0; i < NB; i++) { int v = lds[i]; lds[i] = acc; acc += v; }
    }
    __syncthreads();
    if (t < NB) boff[t] = lds[t];
}

__global__ __launch_bounds__(256) void scatter_scan_kernel(const int* __restrict__ indeg,
                                                           const int* __restrict__ boff,
                                                           int* __restrict__ rowstart) {
    __shared__ int lds[256];
    const int b = blockIdx.x;
    const int t = threadIdx.x;
    int base = b * SB + t * 4;
    int v[4];
    int s = 0;
    #pragma unroll
    for (int j = 0; j < 4; j++) {
        int i = base + j;
        v[j] = (i < NN) ? indeg[i] : 0;
        s += v[j];
    }
    lds[t] = s;
    __syncthreads();
    for (int off = 1; off < 256; off <<= 1) {
        int tmp = (t >= off) ? lds[t - off] : 0;
        __syncthreads();
        lds[t] += tmp;
        __syncthreads();
    }
    int excl = lds[t] - s + boff[b];
    #pragma unroll
    for (int j = 0; j < 4; j++) {
        int i = base + j;
        if (i < NN) rowstart[i] = excl;
        excl += v[j];
    }
    if (b == 0 && t == 0) rowstart[NN] = EE;   // in-degrees sum to E exactly
}

// ---------------- CSR fill: csrcol[rowstart[d] + cursor[d]++] = src ----------------
__global__ void fill_kernel(const int* __restrict__ ei, const int* __restrict__ rowstart,
                            int* __restrict__ cursor, int* __restrict__ csrcol) {
    int e = blockIdx.x * blockDim.x + threadIdx.x;
    if (e < EE) {
        int s = ei[e];
        int d = ei[EE + e];
        int p = atomicAdd(&cursor[d], 1);
        csrcol[rowstart[d] + p] = s;
    }
}

// ---------------- dinv = rsqrt(indeg + 1) ----------------
__global__ void dinv_kernel(const int* __restrict__ indeg, float* __restrict__ dinv) {
    int i = blockIdx.x * blockDim.x + threadIdx.x;
    if (i < NN) dinv[i] = rsqrtf((float)indeg[i] + 1.0f);
}

// ---------------- g = (x @ W1) * dinv[row] — register-tiled fp32 GEMM ----------------
// Block: 256 threads, 64 rows x 256 cols. Thread micro-tile: 8x8 split as
// rows {ra..ra+3, ra+32..ra+35} x cols {ca..ca+3, ca+128..ca+131} so that the
// compute-phase ds_read_b128 pattern is 32 consecutive lanes x consecutive 16B
// (canonical conflict-free) and xs reads are wave-broadcast.
__global__ __launch_bounds__(256) void gemm_kernel(const float* __restrict__ x,
                                                   const float* __restrict__ W1,
                                                   const float* __restrict__ dinv,
                                                   float* __restrict__ g) {
    __shared__ float xs[BK][BM + XPAD];   // x^T tile: 16 x 68 floats = 4.25 KB
    __shared__ float wl[BK][C];           // W tile:  16 x 256 floats = 16 KB
    const int tid = threadIdx.x;
    const int row0 = blockIdx.x * BM;
    const int cg = tid & 31;     // column group
    const int rg = tid >> 5;     // row group
    const int ca = cg * 4;
    const int ra = rg * 4;
    // staging mapping for x: 64 rows x 16 k per tile; thread -> (srow, skq)
    const int srow = tid >> 2;
    const int skq = tid & 3;
    const bool rowok = (row0 + srow) < NN;
    const float* xrowp = x + (size_t)(row0 + srow) * C + skq * 4;

    float4 acc[2][2][4];    // [rowhalf][colhalf][r], float4 over 4 cols
    #pragma unroll
    for (int i = 0; i < 2; i++)
        #pragma unroll
        for (int j = 0; j < 2; j++)
            #pragma unroll
            for (int r = 0; r < 4; r++)
                acc[i][j][r] = make_float4(0.f, 0.f, 0.f, 0.f);

    for (int k0 = 0; k0 < C; k0 += BK) {
        // stage W tile: 1024 float4 / 256 threads = 4 each, coalesced
        #pragma unroll
        for (int j = 0; j < 4; j++) {
            int idx = tid + j * 256;
            int kk = idx >> 6;
            int cc = (idx & 63) * 4;
            *(float4*)&wl[kk][cc] = *(const float4*)&W1[(size_t)(k0 + kk) * C + cc];
        }
        // stage x tile transposed
        float4 xv = rowok ? *(const float4*)(xrowp + k0) : make_float4(0.f, 0.f, 0.f, 0.f);
        xs[skq * 4 + 0][srow] = xv.x;
        xs[skq * 4 + 1][srow] = xv.y;
        xs[skq * 4 + 2][srow] = xv.z;
        xs[skq * 4 + 3][srow] = xv.w;
        __syncthreads();

        #pragma unroll
        for (int kk = 0; kk < BK; kk++) {
            float4 a0 = *(const float4*)&xs[kk][ra];
            float4 a1 = *(const float4*)&xs[kk][ra + 32];
            float4 b0 = *(const float4*)&wl[kk][ca];
            float4 b1 = *(const float4*)&wl[kk][ca + 128];
            float ar0[4] = {a0.x, a0.y, a0.z, a0.w};
            float ar1[4] = {a1.x, a1.y, a1.z, a1.w};
            #pragma unroll
            for (int r = 0; r < 4; r++) {
                acc[0][0][r].x += ar0[r] * b0.x;
                acc[0][0][r].y += ar0[r] * b0.y;
                acc[0][0][r].z += ar0[r] * b0.z;
                acc[0][0][r].w += ar0[r] * b0.w;
                acc[0][1][r].x += ar0[r] * b1.x;
                acc[0][1][r].y += ar0[r] * b1.y;
                acc[0][1][r].z += ar0[r] * b1.z;
                acc[0][1][r].w += ar0[r] * b1.w;
                acc[1][0][r].x += ar1[r] * b0.x;
                acc[1][0][r].y += ar1[r] * b0.y;
                acc[1][0][r].z += ar1[r] * b0.z;
                acc[1][0][r].w += ar1[r] * b0.w;
                acc[1][1][r].x += ar1[r] * b1.x;
                acc[1][1][r].y += ar1[r] * b1.y;
                acc[1][1][r].z += ar1[r] * b1.z;
                acc[1][1][r].w += ar1[r] * b1.w;
            }
        }
        __syncthreads();
    }

    #pragma unroll
    for (int rh = 0; rh < 2; rh++) {
        #pragma unroll
        for (int r = 0; r < 4; r++) {
            int row = row0 + ra + rh * 32 + r;
            if (row < NN) {
                float dv = dinv[row];
                float4 v0 = acc[rh][0][r];
                v0.x *= dv; v0.y *= dv; v0.z *= dv; v0.w *= dv;
                *(float4*)&g[(size_t)row * C + ca] = v0;
                float4 v1 = acc[rh][1][r];
                v1.x *= dv; v1.y *= dv; v1.z *= dv; v1.w *= dv;
                *(float4*)&g[(size_t)row * C + ca + 128] = v1;
            }
        }
    }
}

// ---------------- aggregate + relu + fused mean-pool partial sums ----------------
__global__ __launch_bounds__(256) void agg_pool_kernel(const float* __restrict__ g,
                                                       const int* __restrict__ rowstart,
                                                       const int* __restrict__ csrcol,
                                                       const float* __restrict__ dinv,
                                                       const float* __restrict__ b1,
                                                       const int* __restrict__ batch,
                                                       float* __restrict__ sums) {
    __shared__ int eld[2048];
    const int c = threadIdx.x;
    const int node0 = blockIdx.x * NODES_PER_BLOCK;
    const int node1 = min(node0 + NODES_PER_BLOCK, NN);
    const int e_begin = rowstart[node0];
    const int e_end = rowstart[node1];
    const int ecount = e_end - e_begin;
    const bool use_lds = (ecount <= 2048);
    if (use_lds) {
        for (int e = threadIdx.x; e < ecount; e += 256) eld[e] = csrcol[e_begin + e];
    }
    __syncthreads();

    const float bc = b1[c];
    float pool = 0.0f;
    int curb = -1;
    for (int i = node0; i < node1; i++) {
        int bi = batch[i];
        if (bi != curb) {
            if (curb >= 0) atomicAdd(&sums[curb * C + c], pool);
            curb = bi;
            pool = 0.0f;
        }
        float s = g[(size_t)i * C + c];     // self-loop term (g = h*dinv)
        int r0 = rowstart[i], r1 = rowstart[i + 1];
        if (use_lds) {
            for (int e = r0 - e_begin; e < r1 - e_begin; e++)
                s += g[(size_t)eld[e] * C + c];
        } else {
            for (int e = r0; e < r1; e++)
                s += g[(size_t)csrcol[e] * C + c];
        }
        float a = dinv[i] * s + bc;
        pool += fmaxf(a, 0.0f);
    }
    if (curb >= 0) atomicAdd(&sums[curb * C + c], pool);
}

// ---------------- pooled = sums/cnt; out = pooled @ W2 + b2 ----------------
__global__ __launch_bounds__(256) void final_kernel(const float* __restrict__ sums,
                                                    const float* __restrict__ cnt,
                                                    const float* __restrict__ W2,
                                                    const float* __restrict__ b2,
                                                    float* __restrict__ out) {
    __shared__ float p[C];
    int gi = blockIdx.x;
    float cdiv = fmaxf(cnt[gi], 1.0f);
    p[threadIdx.x] = sums[gi * C + threadIdx.x] / cdiv;
    __syncthreads();
    if (threadIdx.x < OUTC) {
        float acc = b2[threadIdx.x];
        for (int k = 0; k < C; k++) acc += p[k] * W2[k * OUTC + threadIdx.x];
        out[gi * OUTC + threadIdx.x] = acc;
    }
}

extern "C" void kernel_launch(void* const* d_in, const int* in_sizes, int n_in,
                              void* d_out, int out_size, void* d_ws, size_t ws_size,
                              hipStream_t stream) {
    const float* x     = (const float*)d_in[0];
    const int*   ei    = (const int*)d_in[1];   // [2, E] row-major
    const int*   batch = (const int*)d_in[2];
    const float* W1    = (const float*)d_in[3];
    const float* b1    = (const float*)d_in[4];
    const float* W2    = (const float*)d_in[5];
    const float* b2    = (const float*)d_in[6];
    float* out = (float*)d_out;

    char* w = (char*)d_ws;
    size_t off = 0;
    auto carve = [&](size_t bytes) {
        void* p = w + off;
        off = (off + bytes + 255) & ~(size_t)255;
        return p;
    };
    float* g        = (float*)carve((size_t)NN * C * 4);
    int*   indeg    = (int*)  carve((size_t)NN * 4);
    int*   rowstart = (int*)  carve((size_t)(NN + 1) * 4);
    int*   cursor   = (int*)  carve((size_t)NN * 4);
    float* dinv     = (float*)carve((size_t)NN * 4);
    int*   csrcol   = (int*)  carve((size_t)EE * 4);
    float* sums     = (float*)carve((size_t)NG * C * 4);
    float* cnt      = (float*)carve((size_t)NG * 4);
    int*   bsum     = (int*)  carve((size_t)NB * 4);
    int*   boff     = (int*)  carve((size_t)NB * 4);

    hipMemsetAsync(indeg, 0, (size_t)NN * 4, stream);
    hipMemsetAsync(cursor, 0, (size_t)NN * 4, stream);
    hipMemsetAsync(sums, 0, (size_t)NG * C * 4, stream);
    hipMemsetAsync(cnt, 0, (size_t)NG * 4, stream);

    degree_kernel<<<(EE + 255) / 256, 256, 0, stream>>>(ei, indeg);
    count_kernel<<<(NN + 255) / 256, 256, 0, stream>>>(batch, cnt);
    partial_sum_kernel<<<NB, 256, 0, stream>>>(indeg, bsum);
    scan_partials_kernel<<<1, 128, 0, stream>>>(bsum, boff);
    scatter_scan_kernel<<<NB, 256, 0, stream>>>(indeg, boff, rowstart);
    fill_kernel<<<(EE + 255) / 256, 256, 0, stream>>>(ei, rowstart, cursor, csrcol);
    dinv_kernel<<<(NN + 255) / 256, 256, 0, stream>>>(indeg, dinv);
    gemm_kernel<<<(NN + BM - 1) / BM, 256, 0, stream>>>(x, W1, dinv, g);
    agg_pool_kernel<<<(NN + NODES_PER_BLOCK - 1) / NODES_PER_BLOCK, 256, 0, stream>>>(
        g, rowstart, csrcol, dinv, b1, batch, sums);
    final_kernel<<<NG, 256, 0, stream>>>(sums, cnt, W2, b2, out);
}

// Round 3
// 816.917 us; speedup vs baseline: 2.8854x; 1.7818x over previous
//
#include <hip/hip_runtime.h>

#define NN 100000
#define EE 1600000
#define C 256
#define OUTC 10
#define NG 64
#define NODES_PER_BLOCK 8

#define BM 64
#define BK 16
#define XPAD 4        // xs row stride 68 floats: keeps float4 alignment, 2-way-max bank aliasing (free)

#define SB 1024
#define NB ((NN + SB - 1) / SB)

// ---------------- degree histogram (in-degree, real edges only) ----------------
__global__ void degree_kernel(const int* __restrict__ ei, int* __restrict__ indeg) {
    int e = blockIdx.x * blockDim.x + threadIdx.x;
    if (e < EE) {
        int d = ei[EE + e];   // dst row of edge_index [2,E]
        atomicAdd(&indeg[d], 1);
    }
}

// ---------------- per-graph node counts: LDS histogram, 1 global atomic/bin/block ----------------
__global__ __launch_bounds__(1024) void count_kernel(const int* __restrict__ batch,
                                                     float* __restrict__ cnt) {
    __shared__ int h[NG];
    if (threadIdx.x < NG) h[threadIdx.x] = 0;
    __syncthreads();
    int i = blockIdx.x * blockDim.x + threadIdx.x;
    if (i < NN) atomicAdd(&h[batch[i]], 1);
    __syncthreads();
    if (threadIdx.x < NG) {
        int v = h[threadIdx.x];
        if (v > 0) atomicAdd(&cnt[threadIdx.x], (float)v);
    }
}

// ---------------- hierarchical exclusive scan of indeg -> rowstart ----------------
__global__ __launch_bounds__(256) void partial_sum_kernel(const int* __restrict__ indeg,
                                                          int* __restrict__ bsum) {
    __shared__ int red[256];
    const int b = blockIdx.x;
    const int t = threadIdx.x;
    int base = b * SB + t * 4;
    int s = 0;
    #pragma unroll
    for (int j = 0; j < 4; j++) {
        int i = base + j;
        if (i < NN) s += indeg[i];
    }
    red[t] = s;
    __syncthreads();
    for (int off = 128; off > 0; off >>= 1) {
        if (t < off) red[t] += red[t + off];
        __syncthreads();
    }
    if (t == 0) bsum[b] = red[0];
}

__global__ void scan_partials_kernel(const int* __restrict__ bsum, int* __restrict__ boff) {
    __shared__ int lds[NB];
    int t = threadIdx.x;
    if (t < NB) lds[t] = bsum[t];
    __syncthreads();
    if (t == 0) {
        int acc = 0;
        for (int i = 0; i < NB; i++) { int v = lds[i]; lds[i] = acc; acc += v; }
    }
    __syncthreads();
    if (t < NB) boff[t] = lds[t];
}

__global__ __launch_bounds__(256) void scatter_scan_kernel(const int* __restrict__ indeg,
                                                           const int* __restrict__ boff,
                                                           int* __restrict__ rowstart) {
    __shared__ int lds[256];
    const int b = blockIdx.x;
    const int t = threadIdx.x;
    int base = b * SB + t * 4;
    int v[4];
    int s = 0;
    #pragma unroll
    for (int j = 0; j < 4; j++) {
        int i = base + j;
        v[j] = (i < NN) ? indeg[i] : 0;
        s += v[j];
    }
    lds[t] = s;
    __syncthreads();
    for (int off = 1; off < 256; off <<= 1) {
        int tmp = (t >= off) ? lds[t - off] : 0;
        __syncthreads();
        lds[t] += tmp;
        __syncthreads();
    }
    int excl = lds[t] - s + boff[b];
    #pragma unroll
    for (int j = 0; j < 4; j++) {
        int i = base + j;
        if (i < NN) rowstart[i] = excl;
        excl += v[j];
    }
    if (b == 0 && t == 0) rowstart[NN] = EE;   // in-degrees sum to E exactly
}

// ---------------- CSR fill: csrcol[rowstart[d] + cursor[d]++] = src ----------------
__global__ void fill_kernel(const int* __restrict__ ei, const int* __restrict__ rowstart,
                            int* __restrict__ cursor, int* __restrict__ csrcol) {
    int e = blockIdx.x * blockDim.x + threadIdx.x;
    if (e < EE) {
        int s = ei[e];
        int d = ei[EE + e];
        int p = atomicAdd(&cursor[d], 1);
        csrcol[rowstart[d] + p] = s;
    }
}

// ---------------- dinv = rsqrt(indeg + 1) ----------------
__global__ void dinv_kernel(const int* __restrict__ indeg, float* __restrict__ dinv) {
    int i = blockIdx.x * blockDim.x + threadIdx.x;
    if (i < NN) dinv[i] = rsqrtf((float)indeg[i] + 1.0f);
}

// ---------------- g = (x @ W1) * dinv[row] — register-tiled fp32 GEMM ----------------
__global__ __launch_bounds__(256) void gemm_kernel(const float* __restrict__ x,
                                                   const float* __restrict__ W1,
                                                   const float* __restrict__ dinv,
                                                   float* __restrict__ g) {
    __shared__ float xs[BK][BM + XPAD];   // x^T tile: 16 x 68 floats = 4.25 KB
    __shared__ float wl[BK][C];           // W tile:  16 x 256 floats = 16 KB
    const int tid = threadIdx.x;
    const int row0 = blockIdx.x * BM;
    const int cg = tid & 31;     // column group
    const int rg = tid >> 5;     // row group
    const int ca = cg * 4;
    const int ra = rg * 4;
    const int srow = tid >> 2;
    const int skq = tid & 3;
    const bool rowok = (row0 + srow) < NN;
    const float* xrowp = x + (size_t)(row0 + srow) * C + skq * 4;

    float4 acc[2][2][4];
    #pragma unroll
    for (int i = 0; i < 2; i++)
        #pragma unroll
        for (int j = 0; j < 2; j++)
            #pragma unroll
            for (int r = 0; r < 4; r++)
                acc[i][j][r] = make_float4(0.f, 0.f, 0.f, 0.f);

    for (int k0 = 0; k0 < C; k0 += BK) {
        #pragma unroll
        for (int j = 0; j < 4; j++) {
            int idx = tid + j * 256;
            int kk = idx >> 6;
            int cc = (idx & 63) * 4;
            *(float4*)&wl[kk][cc] = *(const float4*)&W1[(size_t)(k0 + kk) * C + cc];
        }
        float4 xv = rowok ? *(const float4*)(xrowp + k0) : make_float4(0.f, 0.f, 0.f, 0.f);
        xs[skq * 4 + 0][srow] = xv.x;
        xs[skq * 4 + 1][srow] = xv.y;
        xs[skq * 4 + 2][srow] = xv.z;
        xs[skq * 4 + 3][srow] = xv.w;
        __syncthreads();

        #pragma unroll
        for (int kk = 0; kk < BK; kk++) {
            float4 a0 = *(const float4*)&xs[kk][ra];
            float4 a1 = *(const float4*)&xs[kk][ra + 32];
            float4 b0 = *(const float4*)&wl[kk][ca];
            float4 b1 = *(const float4*)&wl[kk][ca + 128];
            float ar0[4] = {a0.x, a0.y, a0.z, a0.w};
            float ar1[4] = {a1.x, a1.y, a1.z, a1.w};
            #pragma unroll
            for (int r = 0; r < 4; r++) {
                acc[0][0][r].x += ar0[r] * b0.x;
                acc[0][0][r].y += ar0[r] * b0.y;
                acc[0][0][r].z += ar0[r] * b0.z;
                acc[0][0][r].w += ar0[r] * b0.w;
                acc[0][1][r].x += ar0[r] * b1.x;
                acc[0][1][r].y += ar0[r] * b1.y;
                acc[0][1][r].z += ar0[r] * b1.z;
                acc[0][1][r].w += ar0[r] * b1.w;
                acc[1][0][r].x += ar1[r] * b0.x;
                acc[1][0][r].y += ar1[r] * b0.y;
                acc[1][0][r].z += ar1[r] * b0.z;
                acc[1][0][r].w += ar1[r] * b0.w;
                acc[1][1][r].x += ar1[r] * b1.x;
                acc[1][1][r].y += ar1[r] * b1.y;
                acc[1][1][r].z += ar1[r] * b1.z;
                acc[1][1][r].w += ar1[r] * b1.w;
            }
        }
        __syncthreads();
    }

    #pragma unroll
    for (int rh = 0; rh < 2; rh++) {
        #pragma unroll
        for (int r = 0; r < 4; r++) {
            int row = row0 + ra + rh * 32 + r;
            if (row < NN) {
                float dv = dinv[row];
                float4 v0 = acc[rh][0][r];
                v0.x *= dv; v0.y *= dv; v0.z *= dv; v0.w *= dv;
                *(float4*)&g[(size_t)row * C + ca] = v0;
                float4 v1 = acc[rh][1][r];
                v1.x *= dv; v1.y *= dv; v1.z *= dv; v1.w *= dv;
                *(float4*)&g[(size_t)row * C + ca + 128] = v1;
            }
        }
    }
}

// ---------------- aggregate + relu + fused mean-pool partial sums ----------------
__global__ __launch_bounds__(256) void agg_pool_kernel(const float* __restrict__ g,
                                                       const int* __restrict__ rowstart,
                                                       const int* __restrict__ csrcol,
                                                       const float* __restrict__ dinv,
                                                       const float* __restrict__ b1,
                                                       const int* __restrict__ batch,
                                                       float* __restrict__ sums) {
    __shared__ int eld[2048];
    const int c = threadIdx.x;
    const int node0 = blockIdx.x * NODES_PER_BLOCK;
    const int node1 = min(node0 + NODES_PER_BLOCK, NN);
    const int e_begin = rowstart[node0];
    const int e_end = rowstart[node1];
    const int ecount = e_end - e_begin;
    const bool use_lds = (ecount <= 2048);
    if (use_lds) {
        for (int e = threadIdx.x; e < ecount; e += 256) eld[e] = csrcol[e_begin + e];
    }
    __syncthreads();

    const float bc = b1[c];
    float pool = 0.0f;
    int curb = -1;
    for (int i = node0; i < node1; i++) {
        int bi = batch[i];
        if (bi != curb) {
            if (curb >= 0) atomicAdd(&sums[curb * C + c], pool);
            curb = bi;
            pool = 0.0f;
        }
        float s = g[(size_t)i * C + c];     // self-loop term (g = h*dinv)
        int r0 = rowstart[i], r1 = rowstart[i + 1];
        if (use_lds) {
            for (int e = r0 - e_begin; e < r1 - e_begin; e++)
                s += g[(size_t)eld[e] * C + c];
        } else {
            for (int e = r0; e < r1; e++)
                s += g[(size_t)csrcol[e] * C + c];
        }
        float a = dinv[i] * s + bc;
        pool += fmaxf(a, 0.0f);
    }
    if (curb >= 0) atomicAdd(&sums[curb * C + c], pool);
}

// ---------------- pooled = sums/cnt; out = pooled @ W2 + b2 ----------------
__global__ __launch_bounds__(256) void final_kernel(const float* __restrict__ sums,
                                                    const float* __restrict__ cnt,
                                                    const float* __restrict__ W2,
                                                    const float* __restrict__ b2,
                                                    float* __restrict__ out) {
    __shared__ float p[C];
    int gi = blockIdx.x;
    float cdiv = fmaxf(cnt[gi], 1.0f);
    p[threadIdx.x] = sums[gi * C + threadIdx.x] / cdiv;
    __syncthreads();
    if (threadIdx.x < OUTC) {
        float acc = b2[threadIdx.x];
        for (int k = 0; k < C; k++) acc += p[k] * W2[k * OUTC + threadIdx.x];
        out[gi * OUTC + threadIdx.x] = acc;
    }
}

extern "C" void kernel_launch(void* const* d_in, const int* in_sizes, int n_in,
                              void* d_out, int out_size, void* d_ws, size_t ws_size,
                              hipStream_t stream) {
    const float* x     = (const float*)d_in[0];
    const int*   ei    = (const int*)d_in[1];   // [2, E] row-major
    const int*   batch = (const int*)d_in[2];
    const float* W1    = (const float*)d_in[3];
    const float* b1    = (const float*)d_in[4];
    const float* W2    = (const float*)d_in[5];
    const float* b2    = (const float*)d_in[6];
    float* out = (float*)d_out;

    char* w = (char*)d_ws;
    size_t off = 0;
    auto carve = [&](size_t bytes) {
        void* p = w + off;
        off = (off + bytes + 255) & ~(size_t)255;
        return p;
    };
    float* g        = (float*)carve((size_t)NN * C * 4);
    int*   indeg    = (int*)  carve((size_t)NN * 4);
    int*   rowstart = (int*)  carve((size_t)(NN + 1) * 4);
    int*   cursor   = (int*)  carve((size_t)NN * 4);
    float* dinv     = (float*)carve((size_t)NN * 4);
    int*   csrcol   = (int*)  carve((size_t)EE * 4);
    float* sums     = (float*)carve((size_t)NG * C * 4);
    float* cnt      = (float*)carve((size_t)NG * 4);
    int*   bsum     = (int*)  carve((size_t)NB * 4);
    int*   boff     = (int*)  carve((size_t)NB * 4);

    hipMemsetAsync(indeg, 0, (size_t)NN * 4, stream);
    hipMemsetAsync(cursor, 0, (size_t)NN * 4, stream);
    hipMemsetAsync(sums, 0, (size_t)NG * C * 4, stream);
    hipMemsetAsync(cnt, 0, (size_t)NG * 4, stream);

    degree_kernel<<<(EE + 255) / 256, 256, 0, stream>>>(ei, indeg);
    count_kernel<<<(NN + 1023) / 1024, 1024, 0, stream>>>(batch, cnt);
    partial_sum_kernel<<<NB, 256, 0, stream>>>(indeg, bsum);
    scan_partials_kernel<<<1, 128, 0, stream>>>(bsum, boff);
    scatter_scan_kernel<<<NB, 256, 0, stream>>>(indeg, boff, rowstart);
    fill_kernel<<<(EE + 255) / 256, 256, 0, stream>>>(ei, rowstart, cursor, csrcol);
    dinv_kernel<<<(NN + 255) / 256, 256, 0, stream>>>(indeg, dinv);
    gemm_kernel<<<(NN + BM - 1) / BM, 256, 0, stream>>>(x, W1, dinv, g);
    agg_pool_kernel<<<(NN + NODES_PER_BLOCK - 1) / NODES_PER_BLOCK, 256, 0, stream>>>(
        g, rowstart, csrcol, dinv, b1, batch, sums);
    final_kernel<<<NG, 256, 0, stream>>>(sums, cnt, W2, b2, out);
}

// Round 4
// 659.666 us; speedup vs baseline: 3.5732x; 1.2384x over previous
//
#include <hip/hip_runtime.h>

#define NN 100000
#define EE 1600000
#define C 256
#define OUTC 10
#define NG 64

#define BM 64
#define BK 16
#define XPAD 4

#define SB 1024
#define NB ((NN + SB - 1) / SB)

// agg_pool decomposition: 4 waves/block, each wave owns NODES_PER_GROUP nodes
#define NODES_PER_GROUP 8
#define NODES_PER_BLOCK 32      // 4 waves * 8 nodes; 100000 = 32 * 3125 exactly

// ---------------- bf16 helpers (RNE) ----------------
__device__ __forceinline__ ushort f2bf(float f) {
    unsigned u = __float_as_uint(f);
    return (ushort)((u + 0x7fffu + ((u >> 16) & 1u)) >> 16);
}
__device__ __forceinline__ float bf2f(ushort b) {
    return __uint_as_float(((unsigned)b) << 16);
}

// ---------------- degree histogram (in-degree, real edges only) ----------------
__global__ void degree_kernel(const int* __restrict__ ei, int* __restrict__ indeg) {
    int e = blockIdx.x * blockDim.x + threadIdx.x;
    if (e < EE) {
        int d = ei[EE + e];
        atomicAdd(&indeg[d], 1);
    }
}

// ---------------- per-graph node counts: LDS histogram ----------------
__global__ __launch_bounds__(1024) void count_kernel(const int* __restrict__ batch,
                                                     float* __restrict__ cnt) {
    __shared__ int h[NG];
    if (threadIdx.x < NG) h[threadIdx.x] = 0;
    __syncthreads();
    int i = blockIdx.x * blockDim.x + threadIdx.x;
    if (i < NN) atomicAdd(&h[batch[i]], 1);
    __syncthreads();
    if (threadIdx.x < NG) {
        int v = h[threadIdx.x];
        if (v > 0) atomicAdd(&cnt[threadIdx.x], (float)v);
    }
}

// ---------------- hierarchical exclusive scan of indeg -> rowstart ----------------
__global__ __launch_bounds__(256) void partial_sum_kernel(const int* __restrict__ indeg,
                                                          int* __restrict__ bsum) {
    __shared__ int red[256];
    const int b = blockIdx.x;
    const int t = threadIdx.x;
    int base = b * SB + t * 4;
    int s = 0;
    #pragma unroll
    for (int j = 0; j < 4; j++) {
        int i = base + j;
        if (i < NN) s += indeg[i];
    }
    red[t] = s;
    __syncthreads();
    for (int off = 128; off > 0; off >>= 1) {
        if (t < off) red[t] += red[t + off];
        __syncthreads();
    }
    if (t == 0) bsum[b] = red[0];
}

__global__ void scan_partials_kernel(const int* __restrict__ bsum, int* __restrict__ boff) {
    __shared__ int lds[NB];
    int t = threadIdx.x;
    if (t < NB) lds[t] = bsum[t];
    __syncthreads();
    if (t == 0) {
        int acc = 0;
        for (int i = 0; i < NB; i++) { int v = lds[i]; lds[i] = acc; acc += v; }
    }
    __syncthreads();
    if (t < NB) boff[t] = lds[t];
}

__global__ __launch_bounds__(256) void scatter_scan_kernel(const int* __restrict__ indeg,
                                                           const int* __restrict__ boff,
                                                           int* __restrict__ rowstart) {
    __shared__ int lds[256];
    const int b = blockIdx.x;
    const int t = threadIdx.x;
    int base = b * SB + t * 4;
    int v[4];
    int s = 0;
    #pragma unroll
    for (int j = 0; j < 4; j++) {
        int i = base + j;
        v[j] = (i < NN) ? indeg[i] : 0;
        s += v[j];
    }
    lds[t] = s;
    __syncthreads();
    for (int off = 1; off < 256; off <<= 1) {
        int tmp = (t >= off) ? lds[t - off] : 0;
        __syncthreads();
        lds[t] += tmp;
        __syncthreads();
    }
    int excl = lds[t] - s + boff[b];
    #pragma unroll
    for (int j = 0; j < 4; j++) {
        int i = base + j;
        if (i < NN) rowstart[i] = excl;
        excl += v[j];
    }
    if (b == 0 && t == 0) rowstart[NN] = EE;
}

// ---------------- CSR fill ----------------
__global__ void fill_kernel(const int* __restrict__ ei, const int* __restrict__ rowstart,
                            int* __restrict__ cursor, int* __restrict__ csrcol) {
    int e = blockIdx.x * blockDim.x + threadIdx.x;
    if (e < EE) {
        int s = ei[e];
        int d = ei[EE + e];
        int p = atomicAdd(&cursor[d], 1);
        csrcol[rowstart[d] + p] = s;
    }
}

// ---------------- dinv = rsqrt(indeg + 1) ----------------
__global__ void dinv_kernel(const int* __restrict__ indeg, float* __restrict__ dinv) {
    int i = blockIdx.x * blockDim.x + threadIdx.x;
    if (i < NN) dinv[i] = rsqrtf((float)indeg[i] + 1.0f);
}

// ---------------- g = bf16((x @ W1) * dinv[row]) — register-tiled fp32 GEMM ----------------
__global__ __launch_bounds__(256) void gemm_kernel(const float* __restrict__ x,
                                                   const float* __restrict__ W1,
                                                   const float* __restrict__ dinv,
                                                   ushort* __restrict__ g) {
    __shared__ float xs[BK][BM + XPAD];
    __shared__ float wl[BK][C];
    const int tid = threadIdx.x;
    const int row0 = blockIdx.x * BM;
    const int cg = tid & 31;
    const int rg = tid >> 5;
    const int ca = cg * 4;
    const int ra = rg * 4;
    const int srow = tid >> 2;
    const int skq = tid & 3;
    const bool rowok = (row0 + srow) < NN;
    const float* xrowp = x + (size_t)(row0 + srow) * C + skq * 4;

    float4 acc[2][2][4];
    #pragma unroll
    for (int i = 0; i < 2; i++)
        #pragma unroll
        for (int j = 0; j < 2; j++)
            #pragma unroll
            for (int r = 0; r < 4; r++)
                acc[i][j][r] = make_float4(0.f, 0.f, 0.f, 0.f);

    for (int k0 = 0; k0 < C; k0 += BK) {
        #pragma unroll
        for (int j = 0; j < 4; j++) {
            int idx = tid + j * 256;
            int kk = idx >> 6;
            int cc = (idx & 63) * 4;
            *(float4*)&wl[kk][cc] = *(const float4*)&W1[(size_t)(k0 + kk) * C + cc];
        }
        float4 xv = rowok ? *(const float4*)(xrowp + k0) : make_float4(0.f, 0.f, 0.f, 0.f);
        xs[skq * 4 + 0][srow] = xv.x;
        xs[skq * 4 + 1][srow] = xv.y;
        xs[skq * 4 + 2][srow] = xv.z;
        xs[skq * 4 + 3][srow] = xv.w;
        __syncthreads();

        #pragma unroll
        for (int kk = 0; kk < BK; kk++) {
            float4 a0 = *(const float4*)&xs[kk][ra];
            float4 a1 = *(const float4*)&xs[kk][ra + 32];
            float4 b0 = *(const float4*)&wl[kk][ca];
            float4 b1 = *(const float4*)&wl[kk][ca + 128];
            float ar0[4] = {a0.x, a0.y, a0.z, a0.w};
            float ar1[4] = {a1.x, a1.y, a1.z, a1.w};
            #pragma unroll
            for (int r = 0; r < 4; r++) {
                acc[0][0][r].x += ar0[r] * b0.x;
                acc[0][0][r].y += ar0[r] * b0.y;
                acc[0][0][r].z += ar0[r] * b0.z;
                acc[0][0][r].w += ar0[r] * b0.w;
                acc[0][1][r].x += ar0[r] * b1.x;
                acc[0][1][r].y += ar0[r] * b1.y;
                acc[0][1][r].z += ar0[r] * b1.z;
                acc[0][1][r].w += ar0[r] * b1.w;
                acc[1][0][r].x += ar1[r] * b0.x;
                acc[1][0][r].y += ar1[r] * b0.y;
                acc[1][0][r].z += ar1[r] * b0.z;
                acc[1][0][r].w += ar1[r] * b0.w;
                acc[1][1][r].x += ar1[r] * b1.x;
                acc[1][1][r].y += ar1[r] * b1.y;
                acc[1][1][r].z += ar1[r] * b1.z;
                acc[1][1][r].w += ar1[r] * b1.w;
            }
        }
        __syncthreads();
    }

    #pragma unroll
    for (int rh = 0; rh < 2; rh++) {
        #pragma unroll
        for (int r = 0; r < 4; r++) {
            int row = row0 + ra + rh * 32 + r;
            if (row < NN) {
                float dv = dinv[row];
                float4 v0 = acc[rh][0][r];
                ushort4 o0;
                o0.x = f2bf(v0.x * dv); o0.y = f2bf(v0.y * dv);
                o0.z = f2bf(v0.z * dv); o0.w = f2bf(v0.w * dv);
                *(ushort4*)&g[(size_t)row * C + ca] = o0;
                float4 v1 = acc[rh][1][r];
                ushort4 o1;
                o1.x = f2bf(v1.x * dv); o1.y = f2bf(v1.y * dv);
                o1.z = f2bf(v1.z * dv); o1.w = f2bf(v1.w * dv);
                *(ushort4*)&g[(size_t)row * C + ca + 128] = o1;
            }
        }
    }
}

// ---------------- aggregate + relu + fused mean-pool ----------------
// One wave per node-stream: 64 lanes x 4 ch (ushort4 = 8B) covers a full 512B
// bf16 row in one instruction. Edge loop unrolled x4 for MLP. fp32 accumulate.
__device__ __forceinline__ float4 load_row_bf16(const ushort* __restrict__ g,
                                                int row, int c4) {
    ushort4 v = *(const ushort4*)(g + (size_t)row * C + c4);
    float4 f;
    f.x = bf2f(v.x); f.y = bf2f(v.y); f.z = bf2f(v.z); f.w = bf2f(v.w);
    return f;
}

__global__ __launch_bounds__(256) void agg_pool_kernel(const ushort* __restrict__ g,
                                                       const int* __restrict__ rowstart,
                                                       const int* __restrict__ csrcol,
                                                       const float* __restrict__ dinv,
                                                       const float* __restrict__ b1,
                                                       const int* __restrict__ batch,
                                                       float* __restrict__ sums) {
    const int lane = threadIdx.x & 63;
    const int wid = threadIdx.x >> 6;
    const int c4 = lane * 4;
    const int nodeA = blockIdx.x * NODES_PER_BLOCK + wid * NODES_PER_GROUP;
    const float4 bv = *(const float4*)&b1[c4];

    float4 pool = make_float4(0.f, 0.f, 0.f, 0.f);
    int curb = -1;
    #pragma unroll 1
    for (int i = nodeA; i < nodeA + NODES_PER_GROUP; i++) {
        int bi = batch[i];
        if (bi != curb) {
            if (curb >= 0) {
                atomicAdd(&sums[curb * C + c4 + 0], pool.x);
                atomicAdd(&sums[curb * C + c4 + 1], pool.y);
                atomicAdd(&sums[curb * C + c4 + 2], pool.z);
                atomicAdd(&sums[curb * C + c4 + 3], pool.w);
            }
            curb = bi;
            pool = make_float4(0.f, 0.f, 0.f, 0.f);
        }
        int r0 = rowstart[i], r1 = rowstart[i + 1];
        float4 s = load_row_bf16(g, i, c4);   // self-loop term
        int e = r0;
        for (; e + 4 <= r1; e += 4) {
            int i0 = csrcol[e], i1 = csrcol[e + 1], i2 = csrcol[e + 2], i3 = csrcol[e + 3];
            float4 v0 = load_row_bf16(g, i0, c4);
            float4 v1 = load_row_bf16(g, i1, c4);
            float4 v2 = load_row_bf16(g, i2, c4);
            float4 v3 = load_row_bf16(g, i3, c4);
            s.x += v0.x + v1.x + v2.x + v3.x;
            s.y += v0.y + v1.y + v2.y + v3.y;
            s.z += v0.z + v1.z + v2.z + v3.z;
            s.w += v0.w + v1.w + v2.w + v3.w;
        }
        for (; e < r1; e++) {
            float4 v = load_row_bf16(g, csrcol[e], c4);
            s.x += v.x; s.y += v.y; s.z += v.z; s.w += v.w;
        }
        float dv = dinv[i];
        pool.x += fmaxf(dv * s.x + bv.x, 0.f);
        pool.y += fmaxf(dv * s.y + bv.y, 0.f);
        pool.z += fmaxf(dv * s.z + bv.z, 0.f);
        pool.w += fmaxf(dv * s.w + bv.w, 0.f);
    }
    if (curb >= 0) {
        atomicAdd(&sums[curb * C + c4 + 0], pool.x);
        atomicAdd(&sums[curb * C + c4 + 1], pool.y);
        atomicAdd(&sums[curb * C + c4 + 2], pool.z);
        atomicAdd(&sums[curb * C + c4 + 3], pool.w);
    }
}

// ---------------- pooled = sums/cnt; out = pooled @ W2 + b2 ----------------
__global__ __launch_bounds__(256) void final_kernel(const float* __restrict__ sums,
                                                    const float* __restrict__ cnt,
                                                    const float* __restrict__ W2,
                                                    const float* __restrict__ b2,
                                                    float* __restrict__ out) {
    __shared__ float p[C];
    int gi = blockIdx.x;
    float cdiv = fmaxf(cnt[gi], 1.0f);
    p[threadIdx.x] = sums[gi * C + threadIdx.x] / cdiv;
    __syncthreads();
    if (threadIdx.x < OUTC) {
        float acc = b2[threadIdx.x];
        for (int k = 0; k < C; k++) acc += p[k] * W2[k * OUTC + threadIdx.x];
        out[gi * OUTC + threadIdx.x] = acc;
    }
}

extern "C" void kernel_launch(void* const* d_in, const int* in_sizes, int n_in,
                              void* d_out, int out_size, void* d_ws, size_t ws_size,
                              hipStream_t stream) {
    const float* x     = (const float*)d_in[0];
    const int*   ei    = (const int*)d_in[1];
    const int*   batch = (const int*)d_in[2];
    const float* W1    = (const float*)d_in[3];
    const float* b1    = (const float*)d_in[4];
    const float* W2    = (const float*)d_in[5];
    const float* b2    = (const float*)d_in[6];
    float* out = (float*)d_out;

    char* w = (char*)d_ws;
    size_t off = 0;
    auto carve = [&](size_t bytes) {
        void* p = w + off;
        off = (off + bytes + 255) & ~(size_t)255;
        return p;
    };
    ushort* g       = (ushort*)carve((size_t)NN * C * 2);
    int*   indeg    = (int*)  carve((size_t)NN * 4);
    int*   rowstart = (int*)  carve((size_t)(NN + 1) * 4);
    int*   cursor   = (int*)  carve((size_t)NN * 4);
    float* dinv     = (float*)carve((size_t)NN * 4);
    int*   csrcol   = (int*)  carve((size_t)EE * 4);
    float* sums     = (float*)carve((size_t)NG * C * 4);
    float* cnt      = (float*)carve((size_t)NG * 4);
    int*   bsum     = (int*)  carve((size_t)NB * 4);
    int*   boff     = (int*)  carve((size_t)NB * 4);

    hipMemsetAsync(indeg, 0, (size_t)NN * 4, stream);
    hipMemsetAsync(cursor, 0, (size_t)NN * 4, stream);
    hipMemsetAsync(sums, 0, (size_t)NG * C * 4, stream);
    hipMemsetAsync(cnt, 0, (size_t)NG * 4, stream);

    degree_kernel<<<(EE + 255) / 256, 256, 0, stream>>>(ei, indeg);
    count_kernel<<<(NN + 1023) / 1024, 1024, 0, stream>>>(batch, cnt);
    partial_sum_kernel<<<NB, 256, 0, stream>>>(indeg, bsum);
    scan_partials_kernel<<<1, 128, 0, stream>>>(bsum, boff);
    scatter_scan_kernel<<<NB, 256, 0, stream>>>(indeg, boff, rowstart);
    fill_kernel<<<(EE + 255) / 256, 256, 0, stream>>>(ei, rowstart, cursor, csrcol);
    dinv_kernel<<<(NN + 255) / 256, 256, 0, stream>>>(indeg, dinv);
    gemm_kernel<<<(NN + BM - 1) / BM, 256, 0, stream>>>(x, W1, dinv, g);
    agg_pool_kernel<<<NN / NODES_PER_BLOCK, 256, 0, stream>>>(
        g, rowstart, csrcol, dinv, b1, batch, sums);
    final_kernel<<<NG, 256, 0, stream>>>(sums, cnt, W2, b2, out);
}

// Round 5
// 542.823 us; speedup vs baseline: 4.3423x; 1.2153x over previous
//
#include <hip/hip_runtime.h>

#define NN 100000
#define EE 1600000
#define C 256
#define OUTC 10
#define NG 64

#define SB 1024
#define NB ((NN + SB - 1) / SB)

// agg_pool decomposition: 4 waves/block, each wave owns NODES_PER_GROUP nodes
#define NODES_PER_GROUP 8
#define NODES_PER_BLOCK 32      // 4 waves * 8 nodes; 100000 = 32 * 3125 exactly

typedef __bf16 bf16x8 __attribute__((ext_vector_type(8)));
typedef float f32x4 __attribute__((ext_vector_type(4)));

// ---------------- bf16 helpers (RNE) ----------------
__device__ __forceinline__ ushort f2bf(float f) {
    unsigned u = __float_as_uint(f);
    return (ushort)((u + 0x7fffu + ((u >> 16) & 1u)) >> 16);
}
__device__ __forceinline__ float bf2f(ushort b) {
    return __uint_as_float(((unsigned)b) << 16);
}
__device__ __forceinline__ bf16x8 as_bf16x8(uint4 v) {
    union { uint4 u; bf16x8 b; } c; c.u = v; return c.b;
}

// ---------------- degree histogram (in-degree, real edges only) ----------------
__global__ void degree_kernel(const int* __restrict__ ei, int* __restrict__ indeg) {
    int e = blockIdx.x * blockDim.x + threadIdx.x;
    if (e < EE) {
        int d = ei[EE + e];
        atomicAdd(&indeg[d], 1);
    }
}

// ---------------- per-graph node counts: LDS histogram ----------------
__global__ __launch_bounds__(1024) void count_kernel(const int* __restrict__ batch,
                                                     float* __restrict__ cnt) {
    __shared__ int h[NG];
    if (threadIdx.x < NG) h[threadIdx.x] = 0;
    __syncthreads();
    int i = blockIdx.x * blockDim.x + threadIdx.x;
    if (i < NN) atomicAdd(&h[batch[i]], 1);
    __syncthreads();
    if (threadIdx.x < NG) {
        int v = h[threadIdx.x];
        if (v > 0) atomicAdd(&cnt[threadIdx.x], (float)v);
    }
}

// ---------------- hierarchical exclusive scan of indeg -> rowstart ----------------
__global__ __launch_bounds__(256) void partial_sum_kernel(const int* __restrict__ indeg,
                                                          int* __restrict__ bsum) {
    __shared__ int red[256];
    const int b = blockIdx.x;
    const int t = threadIdx.x;
    int base = b * SB + t * 4;
    int s = 0;
    #pragma unroll
    for (int j = 0; j < 4; j++) {
        int i = base + j;
        if (i < NN) s += indeg[i];
    }
    red[t] = s;
    __syncthreads();
    for (int off = 128; off > 0; off >>= 1) {
        if (t < off) red[t] += red[t + off];
        __syncthreads();
    }
    if (t == 0) bsum[b] = red[0];
}

__global__ void scan_partials_kernel(const int* __restrict__ bsum, int* __restrict__ boff) {
    __shared__ int lds[NB];
    int t = threadIdx.x;
    if (t < NB) lds[t] = bsum[t];
    __syncthreads();
    if (t == 0) {
        int acc = 0;
        for (int i = 0; i < NB; i++) { int v = lds[i]; lds[i] = acc; acc += v; }
    }
    __syncthreads();
    if (t < NB) boff[t] = lds[t];
}

__global__ __launch_bounds__(256) void scatter_scan_kernel(const int* __restrict__ indeg,
                                                           const int* __restrict__ boff,
                                                           int* __restrict__ rowstart) {
    __shared__ int lds[256];
    const int b = blockIdx.x;
    const int t = threadIdx.x;
    int base = b * SB + t * 4;
    int v[4];
    int s = 0;
    #pragma unroll
    for (int j = 0; j < 4; j++) {
        int i = base + j;
        v[j] = (i < NN) ? indeg[i] : 0;
        s += v[j];
    }
    lds[t] = s;
    __syncthreads();
    for (int off = 1; off < 256; off <<= 1) {
        int tmp = (t >= off) ? lds[t - off] : 0;
        __syncthreads();
        lds[t] += tmp;
        __syncthreads();
    }
    int excl = lds[t] - s + boff[b];
    #pragma unroll
    for (int j = 0; j < 4; j++) {
        int i = base + j;
        if (i < NN) rowstart[i] = excl;
        excl += v[j];
    }
    if (b == 0 && t == 0) rowstart[NN] = EE;
}

// ---------------- CSR fill ----------------
__global__ void fill_kernel(const int* __restrict__ ei, const int* __restrict__ rowstart,
                            int* __restrict__ cursor, int* __restrict__ csrcol) {
    int e = blockIdx.x * blockDim.x + threadIdx.x;
    if (e < EE) {
        int s = ei[e];
        int d = ei[EE + e];
        int p = atomicAdd(&cursor[d], 1);
        csrcol[rowstart[d] + p] = s;
    }
}

// ---------------- dinv = rsqrt(indeg + 1) ----------------
__global__ void dinv_kernel(const int* __restrict__ indeg, float* __restrict__ dinv) {
    int i = blockIdx.x * blockDim.x + threadIdx.x;
    if (i < NN) dinv[i] = rsqrtf((float)indeg[i] + 1.0f);
}

// ---------------- W1 -> bf16 fragment-order pack ----------------
// b_frag element j of lane L for (kb,nt): W1[kb*32 + (L>>4)*8 + j][nt*16 + (L&15)]
// stored at w1f[((kb*16+nt)*64 + L)*8 + j]
__global__ __launch_bounds__(256) void w1pack_kernel(const float* __restrict__ W1,
                                                     ushort* __restrict__ w1f) {
    int t = blockIdx.x * 256 + threadIdx.x;   // 0..65535 = k*256 + n
    int k = t >> 8, n = t & 255;
    int kb = k >> 5, q = (k >> 3) & 3, j = k & 7;
    int nt = n >> 4, ln = (n & 15) + q * 16;
    w1f[(size_t)(((kb * 16 + nt) * 64) + ln) * 8 + j] = f2bf(W1[t]);
}

// ---------------- g = bf16((x @ W1) * dinv[row]) — MFMA, LDS-free ----------------
// One wave owns 32 rows x 256 cols. A-frags from x (fp32->bf16 in-register),
// B-frags straight from L2-resident w1f. No LDS, no barriers.
__global__ __launch_bounds__(256) void gemm_mfma_kernel(const float* __restrict__ x,
                                                        const ushort* __restrict__ w1f,
                                                        const float* __restrict__ dinv,
                                                        ushort* __restrict__ g) {
    const int lane = threadIdx.x & 63;
    const int wid = threadIdx.x >> 6;
    const int wave = blockIdx.x * 4 + wid;
    const int r0 = wave * 32;
    if (r0 >= NN) return;                 // NN % 32 == 0: whole wave valid or not
    const int mrow = lane & 15;
    const int q = lane >> 4;

    f32x4 acc[2][16];
    #pragma unroll
    for (int mt = 0; mt < 2; mt++)
        #pragma unroll
        for (int nt = 0; nt < 16; nt++)
            acc[mt][nt] = (f32x4){0.f, 0.f, 0.f, 0.f};

    const float* xp0 = x + (size_t)(r0 + mrow) * C + q * 8;       // mt = 0
    const float* xp1 = xp0 + (size_t)16 * C;                      // mt = 1
    const ushort* bp = w1f + (size_t)lane * 8;

    #pragma unroll 1
    for (int kb = 0; kb < 8; kb++) {
        const int ko = kb * 32;
        float4 a0lo = *(const float4*)(xp0 + ko);
        float4 a0hi = *(const float4*)(xp0 + ko + 4);
        float4 a1lo = *(const float4*)(xp1 + ko);
        float4 a1hi = *(const float4*)(xp1 + ko + 4);
        bf16x8 a0, a1;
        a0[0] = (__bf16)a0lo.x; a0[1] = (__bf16)a0lo.y;
        a0[2] = (__bf16)a0lo.z; a0[3] = (__bf16)a0lo.w;
        a0[4] = (__bf16)a0hi.x; a0[5] = (__bf16)a0hi.y;
        a0[6] = (__bf16)a0hi.z; a0[7] = (__bf16)a0hi.w;
        a1[0] = (__bf16)a1lo.x; a1[1] = (__bf16)a1lo.y;
        a1[2] = (__bf16)a1lo.z; a1[3] = (__bf16)a1lo.w;
        a1[4] = (__bf16)a1hi.x; a1[5] = (__bf16)a1hi.y;
        a1[6] = (__bf16)a1hi.z; a1[7] = (__bf16)a1hi.w;

        const ushort* bkb = bp + (size_t)kb * 16 * 512;
        #pragma unroll
        for (int nt = 0; nt < 16; nt++) {
            bf16x8 b = as_bf16x8(*(const uint4*)(bkb + (size_t)nt * 512));
            acc[0][nt] = __builtin_amdgcn_mfma_f32_16x16x32_bf16(a0, b, acc[0][nt], 0, 0, 0);
            acc[1][nt] = __builtin_amdgcn_mfma_f32_16x16x32_bf16(a1, b, acc[1][nt], 0, 0, 0);
        }
    }

    // epilogue: D row = r0 + mt*16 + q*4 + r, col = nt*16 + mrow
    #pragma unroll
    for (int mt = 0; mt < 2; mt++) {
        #pragma unroll
        for (int r = 0; r < 4; r++) {
            int row = r0 + mt * 16 + q * 4 + r;
            float dv = dinv[row];
            ushort* gp = g + (size_t)row * C + mrow;
            #pragma unroll
            for (int nt = 0; nt < 16; nt++)
                gp[nt * 16] = f2bf(acc[mt][nt][r] * dv);
        }
    }
}

// ---------------- aggregate + relu + fused mean-pool ----------------
__device__ __forceinline__ float4 load_row_bf16(const ushort* __restrict__ g,
                                                int row, int c4) {
    ushort4 v = *(const ushort4*)(g + (size_t)row * C + c4);
    float4 f;
    f.x = bf2f(v.x); f.y = bf2f(v.y); f.z = bf2f(v.z); f.w = bf2f(v.w);
    return f;
}

__global__ __launch_bounds__(256) void agg_pool_kernel(const ushort* __restrict__ g,
                                                       const int* __restrict__ rowstart,
                                                       const int* __restrict__ csrcol,
                                                       const float* __restrict__ dinv,
                                                       const float* __restrict__ b1,
                                                       const int* __restrict__ batch,
                                                       float* __restrict__ sums) {
    const int lane = threadIdx.x & 63;
    const int wid = threadIdx.x >> 6;
    const int c4 = lane * 4;
    const int nodeA = blockIdx.x * NODES_PER_BLOCK + wid * NODES_PER_GROUP;
    const float4 bv = *(const float4*)&b1[c4];

    float4 pool = make_float4(0.f, 0.f, 0.f, 0.f);
    int curb = -1;
    #pragma unroll 1
    for (int i = nodeA; i < nodeA + NODES_PER_GROUP; i++) {
        int bi = batch[i];
        if (bi != curb) {
            if (curb >= 0) {
                atomicAdd(&sums[curb * C + c4 + 0], pool.x);
                atomicAdd(&sums[curb * C + c4 + 1], pool.y);
                atomicAdd(&sums[curb * C + c4 + 2], pool.z);
                atomicAdd(&sums[curb * C + c4 + 3], pool.w);
            }
            curb = bi;
            pool = make_float4(0.f, 0.f, 0.f, 0.f);
        }
        int r0 = rowstart[i], r1 = rowstart[i + 1];
        float4 s = load_row_bf16(g, i, c4);   // self-loop term
        int e = r0;
        for (; e + 4 <= r1; e += 4) {
            int i0 = csrcol[e], i1 = csrcol[e + 1], i2 = csrcol[e + 2], i3 = csrcol[e + 3];
            float4 v0 = load_row_bf16(g, i0, c4);
            float4 v1 = load_row_bf16(g, i1, c4);
            float4 v2 = load_row_bf16(g, i2, c4);
            float4 v3 = load_row_bf16(g, i3, c4);
            s.x += v0.x + v1.x + v2.x + v3.x;
            s.y += v0.y + v1.y + v2.y + v3.y;
            s.z += v0.z + v1.z + v2.z + v3.z;
            s.w += v0.w + v1.w + v2.w + v3.w;
        }
        for (; e < r1; e++) {
            float4 v = load_row_bf16(g, csrcol[e], c4);
            s.x += v.x; s.y += v.y; s.z += v.z; s.w += v.w;
        }
        float dv = dinv[i];
        pool.x += fmaxf(dv * s.x + bv.x, 0.f);
        pool.y += fmaxf(dv * s.y + bv.y, 0.f);
        pool.z += fmaxf(dv * s.z + bv.z, 0.f);
        pool.w += fmaxf(dv * s.w + bv.w, 0.f);
    }
    if (curb >= 0) {
        atomicAdd(&sums[curb * C + c4 + 0], pool.x);
        atomicAdd(&sums[curb * C + c4 + 1], pool.y);
        atomicAdd(&sums[curb * C + c4 + 2], pool.z);
        atomicAdd(&sums[curb * C + c4 + 3], pool.w);
    }
}

// ---------------- pooled = sums/cnt; out = pooled @ W2 + b2 ----------------
__global__ __launch_bounds__(256) void final_kernel(const float* __restrict__ sums,
                                                    const float* __restrict__ cnt,
                                                    const float* __restrict__ W2,
                                                    const float* __restrict__ b2,
                                                    float* __restrict__ out) {
    __shared__ float p[C];
    int gi = blockIdx.x;
    float cdiv = fmaxf(cnt[gi], 1.0f);
    p[threadIdx.x] = sums[gi * C + threadIdx.x] / cdiv;
    __syncthreads();
    if (threadIdx.x < OUTC) {
        float acc = b2[threadIdx.x];
        for (int k = 0; k < C; k++) acc += p[k] * W2[k * OUTC + threadIdx.x];
        out[gi * OUTC + threadIdx.x] = acc;
    }
}

extern "C" void kernel_launch(void* const* d_in, const int* in_sizes, int n_in,
                              void* d_out, int out_size, void* d_ws, size_t ws_size,
                              hipStream_t stream) {
    const float* x     = (const float*)d_in[0];
    const int*   ei    = (const int*)d_in[1];
    const int*   batch = (const int*)d_in[2];
    const float* W1    = (const float*)d_in[3];
    const float* b1    = (const float*)d_in[4];
    const float* W2    = (const float*)d_in[5];
    const float* b2    = (const float*)d_in[6];
    float* out = (float*)d_out;

    char* w = (char*)d_ws;
    size_t off = 0;
    auto carve = [&](size_t bytes) {
        void* p = w + off;
        off = (off + bytes + 255) & ~(size_t)255;
        return p;
    };
    ushort* g       = (ushort*)carve((size_t)NN * C * 2);
    int*   indeg    = (int*)  carve((size_t)NN * 4);
    int*   rowstart = (int*)  carve((size_t)(NN + 1) * 4);
    int*   cursor   = (int*)  carve((size_t)NN * 4);
    float* dinv     = (float*)carve((size_t)NN * 4);
    int*   csrcol   = (int*)  carve((size_t)EE * 4);
    float* sums     = (float*)carve((size_t)NG * C * 4);
    float* cnt      = (float*)carve((size_t)NG * 4);
    int*   bsum     = (int*)  carve((size_t)NB * 4);
    int*   boff     = (int*)  carve((size_t)NB * 4);
    ushort* w1f     = (ushort*)carve((size_t)C * C * 2);

    hipMemsetAsync(indeg, 0, (size_t)NN * 4, stream);
    hipMemsetAsync(cursor, 0, (size_t)NN * 4, stream);
    hipMemsetAsync(sums, 0, (size_t)NG * C * 4, stream);
    hipMemsetAsync(cnt, 0, (size_t)NG * 4, stream);

    degree_kernel<<<(EE + 255) / 256, 256, 0, stream>>>(ei, indeg);
    count_kernel<<<(NN + 1023) / 1024, 1024, 0, stream>>>(batch, cnt);
    partial_sum_kernel<<<NB, 256, 0, stream>>>(indeg, bsum);
    scan_partials_kernel<<<1, 128, 0, stream>>>(bsum, boff);
    scatter_scan_kernel<<<NB, 256, 0, stream>>>(indeg, boff, rowstart);
    fill_kernel<<<(EE + 255) / 256, 256, 0, stream>>>(ei, rowstart, cursor, csrcol);
    dinv_kernel<<<(NN + 255) / 256, 256, 0, stream>>>(indeg, dinv);
    w1pack_kernel<<<C * C / 256, 256, 0, stream>>>(W1, w1f);
    gemm_mfma_kernel<<<(NN / 32 + 3) / 4, 256, 0, stream>>>(x, w1f, dinv, g);
    agg_pool_kernel<<<NN / NODES_PER_BLOCK, 256, 0, stream>>>(
        g, rowstart, csrcol, dinv, b1, batch, sums);
    final_kernel<<<NG, 256, 0, stream>>>(sums, cnt, W2, b2, out);
}